// Round 12
// baseline (51.634 us; speedup 1.0000x reference)
//
#include <hip/hip_runtime.h>
#include <math.h>

#define B_  2048
#define T_  200
#define D_  64
#define H1_ 80
#define H2_ 40

#define VSTR 72    // s_V row stride (bf16): 144 B rows -> ~2-way banks
#define WSTR 104   // ws W2T row stride (bf16)
#define HSTR 104   // h1 row stride (bf16); cols 80..95 zero pad

// d_ws layout (bytes):
#define WS_A    0        // A[h][f]  bf16 [80][64]
#define WS_C    10240    // C[h][f]  bf16 [80][64]
#define WS_W2T  20480    // W2Tp[g][h] bf16 [48][104]
#define WS_ACT  30464    // W1acT[h][f] f32 [80][64]

typedef __bf16 bf16x8 __attribute__((ext_vector_type(8)));
typedef float  f32x4  __attribute__((ext_vector_type(4)));

__device__ __forceinline__ float sigmoidf_(float x) {
    return __builtin_amdgcn_rcpf(1.0f + __expf(-x));
}

// ---------- prep: block-invariant weight transforms ----------
__global__ __launch_bounds__(256)
void prep_kernel(const float* __restrict__ W1, const float* __restrict__ W2,
                 void* __restrict__ ws)
{
    __bf16* A    = (__bf16*)((char*)ws + WS_A);
    __bf16* C    = (__bf16*)((char*)ws + WS_C);
    __bf16* W2Tp = (__bf16*)((char*)ws + WS_W2T);
    float*  acT  = (float*)((char*)ws + WS_ACT);
    const int e0 = blockIdx.x * 256 + threadIdx.x;

    for (int e = e0; e < H1_ * D_; e += 2048) {
        int h = e >> 6, f = e & 63;
        float wb = W1[(64  + f) * H1_ + h];
        float wc = W1[(128 + f) * H1_ + h];
        float wd = W1[(192 + f) * H1_ + h];
        float wa = W1[f * H1_ + h];
        A[e]   = (__bf16)(wb - wc);
        C[e]   = (__bf16)wd;
        acT[e] = wa + wc;
    }
    for (int e = e0; e < 48 * WSTR; e += 2048) {
        int g = e / WSTR, h = e - g * WSTR;
        W2Tp[e] = (g < H2_ && h < H1_) ? (__bf16)W2[h * H2_ + g] : (__bf16)0.0f;
    }
}

// ---------- main: one batch per 2-wave block (tile-parity split) ----------
__global__ __launch_bounds__(128, 3)
void attn_din12(const float* __restrict__ query,
                const float* __restrict__ key,
                const int*   __restrict__ mask,
                const float* __restrict__ b1,
                const float* __restrict__ b2,
                const float* __restrict__ W3,
                const float* __restrict__ b3,
                const void*  __restrict__ ws,
                float* __restrict__ out)
{
    __shared__ __align__(16) __bf16 s_V[H1_ * VSTR];     // 11520 B (block-shared)
    __shared__ __align__(16) __bf16 s_h1[2][16 * HSTR];  //  6656 B (per-wave)
    __shared__ float s_scf[208];                          //   832 B
    __shared__ float s_q[D_];                             //   256 B
    __shared__ float s_base[H1_];                         //   320 B
    __shared__ float s_part[2][D_];                       //   512 B
    __shared__ float s_red[4];
    // ~20.1 KB -> 6+ blocks/CU at 3 waves/SIMD

    const int tid  = threadIdx.x;          // 0..127
    const int lane = tid & 63;
    const int w    = tid >> 6;             // wave 0/1
    const int c16  = lane & 15;
    const int g16  = lane >> 4;
    const int b    = blockIdx.x;           // one batch per block

    const int   mv     = mask[b];
    const int   ntiles = (mv + 15) >> 4;
    const float b3v    = b3[0];
    const float* kb = key + (size_t)b * T_ * D_;

    const __bf16* wsA   = (const __bf16*)((const char*)ws + WS_A);
    const __bf16* wsC   = (const __bf16*)((const char*)ws + WS_C);
    const __bf16* wsW2T = (const __bf16*)((const char*)ws + WS_W2T);
    const float*  wsacT = (const float*) ((const char*)ws + WS_ACT);

    // ---- stage q (wave 0), init scores, load W2T fragments to registers ----
    if (w == 0) s_q[lane] = query[b * D_ + lane];
    for (int i = tid; i < 208; i += 128) s_scf[i] = -1e30f;

    bf16x8 bw[3][3];
    #pragma unroll
    for (int nt = 0; nt < 3; ++nt)
        #pragma unroll
        for (int ks = 0; ks < 3; ++ks)
            bw[nt][ks] = *(const bf16x8*)&wsW2T[(nt * 16 + c16) * WSTR + ks * 32 + g16 * 8];

    float b2c[3], w3c[3];
    #pragma unroll
    for (int nt = 0; nt < 3; ++nt) {
        int g = nt * 16 + c16;
        b2c[nt] = (g < H2_) ? b2[g] : 0.0f;
        w3c[nt] = (g < H2_) ? W3[g] : 0.0f;
    }
    __syncthreads();

    // ---- joint V = A + q*C (640 chunks over 128 threads) ----
    #pragma unroll
    for (int i = 0; i < 5; ++i) {
        int e = tid + 128 * i;
        int h = e >> 3, f8 = e & 7;
        bf16x8 a8 = *(const bf16x8*)&wsA[e * 8];
        bf16x8 c8 = *(const bf16x8*)&wsC[e * 8];
        f32x4 q0 = *(const f32x4*)&s_q[f8 * 8];
        f32x4 q1 = *(const f32x4*)&s_q[f8 * 8 + 4];
        bf16x8 v8;
        v8[0] = (__bf16)((float)a8[0] + q0[0] * (float)c8[0]);
        v8[1] = (__bf16)((float)a8[1] + q0[1] * (float)c8[1]);
        v8[2] = (__bf16)((float)a8[2] + q0[2] * (float)c8[2]);
        v8[3] = (__bf16)((float)a8[3] + q0[3] * (float)c8[3]);
        v8[4] = (__bf16)((float)a8[4] + q1[0] * (float)c8[4]);
        v8[5] = (__bf16)((float)a8[5] + q1[1] * (float)c8[5]);
        v8[6] = (__bf16)((float)a8[6] + q1[2] * (float)c8[6]);
        v8[7] = (__bf16)((float)a8[7] + q1[3] * (float)c8[7]);
        *(bf16x8*)&s_V[h * VSTR + f8 * 8] = v8;
    }

    // ---- base[h] (threads 0..79, one h each) ----
    if (tid < H1_) {
        float a0 = b1[tid], a1 = 0.0f, a2 = 0.0f, a3 = 0.0f;
        const f32x4* row = (const f32x4*)&wsacT[tid * D_];
        #pragma unroll
        for (int f4 = 0; f4 < 16; ++f4) {
            f32x4 v  = row[f4];
            f32x4 q4 = *(const f32x4*)&s_q[f4 * 4];
            a0 = fmaf(q4[0], v[0], a0);
            a1 = fmaf(q4[1], v[1], a1);
            a2 = fmaf(q4[2], v[2], a2);
            a3 = fmaf(q4[3], v[3], a3);
        }
        s_base[tid] = (a0 + a1) + (a2 + a3);
    }

    // ---- zero h1 pad cols 80..95 (own wave tile, once) ----
    {
        int row = lane & 15, c0 = 80 + (lane >> 4) * 4;
        *(uint2*)&s_h1[w][row * HSTR + c0] = make_uint2(0u, 0u);
    }
    __syncthreads();

    float base_c[5];
    #pragma unroll
    for (int nt = 0; nt < 5; ++nt) base_c[nt] = s_base[nt * 16 + c16];
    __bf16* myh = &s_h1[w][0];

    // ---- prologue key load for first own tile (clamped rows; safe even if unused) ----
    float4 u0, u1, u2, u3;
    {
        int tr = w * 16 + c16;
        const float* kr = kb + (size_t)((tr < T_) ? tr : (T_ - 1)) * D_ + g16 * 8;
        u0 = *(const float4*)(kr);
        u1 = *(const float4*)(kr + 4);
        u2 = *(const float4*)(kr + 32);
        u3 = *(const float4*)(kr + 36);
    }

    // ---------------- main loop: own-parity tiles ----------------
    for (int tt = w; tt < ntiles; tt += 2) {
        bf16x8 af0, af1;
        af0[0] = (__bf16)u0.x; af0[1] = (__bf16)u0.y; af0[2] = (__bf16)u0.z; af0[3] = (__bf16)u0.w;
        af0[4] = (__bf16)u1.x; af0[5] = (__bf16)u1.y; af0[6] = (__bf16)u1.z; af0[7] = (__bf16)u1.w;
        af1[0] = (__bf16)u2.x; af1[1] = (__bf16)u2.y; af1[2] = (__bf16)u2.z; af1[3] = (__bf16)u2.w;
        af1[4] = (__bf16)u3.x; af1[5] = (__bf16)u3.y; af1[6] = (__bf16)u3.z; af1[7] = (__bf16)u3.w;

        // T14 prefetch next own-parity tile
        if (tt + 2 < ntiles) {
            int tr = (tt + 2) * 16 + c16;
            const float* kr = kb + (size_t)((tr < T_) ? tr : (T_ - 1)) * D_ + g16 * 8;
            u0 = *(const float4*)(kr);
            u1 = *(const float4*)(kr + 4);
            u2 = *(const float4*)(kr + 32);
            u3 = *(const float4*)(kr + 36);
        }

        // layer 1 -> sigmoid -> h1 (own-wave region; B from shared s_V)
        #pragma unroll
        for (int nt = 0; nt < 5; ++nt) {
            float bb = base_c[nt];
            f32x4 c = { bb, bb, bb, bb };
            bf16x8 bv0 = *(const bf16x8*)&s_V[(nt * 16 + c16) * VSTR + g16 * 8];
            bf16x8 bv1 = *(const bf16x8*)&s_V[(nt * 16 + c16) * VSTR + 32 + g16 * 8];
            c = __builtin_amdgcn_mfma_f32_16x16x32_bf16(af0, bv0, c, 0, 0, 0);
            c = __builtin_amdgcn_mfma_f32_16x16x32_bf16(af1, bv1, c, 0, 0, 0);
            #pragma unroll
            for (int r = 0; r < 4; ++r)
                myh[(g16 * 4 + r) * HSTR + nt * 16 + c16] = (__bf16)sigmoidf_(c[r]);
        }

        // layer 2 (k=0..95 incl. zero pad), B from registers
        bf16x8 a2_0 = *(const bf16x8*)&myh[c16 * HSTR + g16 * 8];
        bf16x8 a2_1 = *(const bf16x8*)&myh[c16 * HSTR + 32 + g16 * 8];
        bf16x8 a2_2 = *(const bf16x8*)&myh[c16 * HSTR + 64 + g16 * 8];
        f32x4 acc2[3];
        #pragma unroll
        for (int nt = 0; nt < 3; ++nt) {
            float bb = b2c[nt];
            f32x4 c = { bb, bb, bb, bb };
            c = __builtin_amdgcn_mfma_f32_16x16x32_bf16(a2_0, bw[nt][0], c, 0, 0, 0);
            c = __builtin_amdgcn_mfma_f32_16x16x32_bf16(a2_1, bw[nt][1], c, 0, 0, 0);
            c = __builtin_amdgcn_mfma_f32_16x16x32_bf16(a2_2, bw[nt][2], c, 0, 0, 0);
            acc2[nt] = c;
        }

        // layer 3 + masked score
        const int tb = tt * 16;
        #pragma unroll
        for (int r = 0; r < 4; ++r) {
            float partial = sigmoidf_(acc2[0][r]) * w3c[0]
                          + sigmoidf_(acc2[1][r]) * w3c[1]
                          + sigmoidf_(acc2[2][r]) * w3c[2];
            partial += __shfl_xor(partial, 1);
            partial += __shfl_xor(partial, 2);
            partial += __shfl_xor(partial, 4);
            partial += __shfl_xor(partial, 8);
            int t = tb + g16 * 4 + r;
            if (c16 == 0 && t < mv)
                s_scf[t] = (partial + b3v) * 0.125f;   // / sqrt(64)
        }
    }
    __syncthreads();

    // ---------------- joint softmax over 208 slots (128 threads) ----------------
    float s0 = s_scf[tid];
    float s1 = (tid + 128 < 208) ? s_scf[tid + 128] : -1e30f;
    float m = fmaxf(s0, s1);
    #pragma unroll
    for (int off = 32; off >= 1; off >>= 1) m = fmaxf(m, __shfl_xor(m, off));
    if (lane == 0) s_red[w] = m;
    __syncthreads();
    m = fmaxf(s_red[0], s_red[1]);
    float p0 = __expf(s0 - m);
    float p1 = (tid + 128 < 208) ? __expf(s1 - m) : 0.0f;
    float ps = p0 + p1;
    #pragma unroll
    for (int off = 32; off >= 1; off >>= 1) ps += __shfl_xor(ps, off);
    if (lane == 0) s_red[2 + w] = ps;
    __syncthreads();
    float inv_total = __builtin_amdgcn_rcpf(s_red[2] + s_red[3]);
    s_scf[tid] = p0;
    if (tid + 128 < 208) s_scf[tid + 128] = p1;
    __syncthreads();

    // ---------------- epilogue: parity-split weighted sum ----------------
    float a0 = 0.0f, a1 = 0.0f, a2s = 0.0f, a3s = 0.0f;
    for (int tt = w; tt < ntiles; tt += 2) {
        int t0 = tt * 16;
        int tend = (t0 + 16 < mv) ? (t0 + 16) : mv;
        int t = t0;
        for (; t + 4 <= tend; t += 4) {
            a0  = fmaf(s_scf[t],     kb[(t)     * D_ + lane], a0);
            a1  = fmaf(s_scf[t + 1], kb[(t + 1) * D_ + lane], a1);
            a2s = fmaf(s_scf[t + 2], kb[(t + 2) * D_ + lane], a2s);
            a3s = fmaf(s_scf[t + 3], kb[(t + 3) * D_ + lane], a3s);
        }
        for (; t < tend; ++t)
            a0 = fmaf(s_scf[t], kb[t * D_ + lane], a0);
    }
    s_part[w][lane] = (a0 + a1) + (a2s + a3s);
    __syncthreads();
    if (tid < D_)
        out[b * D_ + tid] = (s_part[0][tid] + s_part[1][tid]) * inv_total;
}

extern "C" void kernel_launch(void* const* d_in, const int* in_sizes, int n_in,
                              void* d_out, int out_size, void* d_ws, size_t ws_size,
                              hipStream_t stream)
{
    const float* query = (const float*)d_in[0];
    const float* key   = (const float*)d_in[1];
    const int*   mask  = (const int*)  d_in[2];
    const float* W1    = (const float*)d_in[3];
    const float* b1    = (const float*)d_in[4];
    const float* W2    = (const float*)d_in[5];
    const float* b2    = (const float*)d_in[6];
    const float* W3    = (const float*)d_in[7];
    const float* b3    = (const float*)d_in[8];
    float* out = (float*)d_out;

    prep_kernel<<<8, 256, 0, stream>>>(W1, W2, d_ws);
    attn_din12<<<B_, 128, 0, stream>>>(query, key, mask, b1, b2, W3, b3, d_ws, out);
}